// Round 6
// baseline (9414.509 us; speedup 1.0000x reference)
//
#include <hip/hip_runtime.h>

#define TT 512
#define BH 65536            // B*H elements (64*1024)
#define NBLK 256

typedef unsigned short u16;
typedef __attribute__((ext_vector_type(8))) __bf16 bf16x8;
typedef __attribute__((ext_vector_type(4))) float f32x4;
typedef __attribute__((ext_vector_type(4))) float float4_t;
typedef __attribute__((ext_vector_type(2))) unsigned long long u64x2;

// workspace layout
#define WS_XBF   0ull
#define WS_H1    67108864ull                 // 4 slots * BH * 2B = 524288
#define WS_H2    (WS_H1 + 524288ull)
#define WS_FLG   (WS_H2 + 524288ull)         // 29056 ints (flag block, 64B-strided entries)
#define WS_PART  (WS_FLG + 131072ull)        // 128 pairs * 2 slots * 16 KiB

// flag map (int offsets within WS_FLG); every entry strided 16 ints (64 B):
//   rdy0 : entry e=(t+1)   at [e*16]          target 64  (h1[t] ready)
//   rdy1 : entry e=(t+1)   at [F_RDY1+e*16]   target 64  (h2[t] ready)
//   con0 : entry e=(t+4)   at [F_CON0+e*16]   target 128 (h1[t] consumed by layer-1)
//          writer of h1[t] polls entry t; entries 0..3 pre-seeded 128
//   pflag: [F_PFLAG+pg*16]  secondary->primary, value t+1
//   pdone: [F_PDONE+pg*16]  primary->secondary, value t+1
#define F_RDY1  8320
#define F_CON0  16640
#define F_PFLAG 24960
#define F_PDONE 27008
#define NFLAG_INTS 29056

// Weights in LDS, MFMA-fragment order: per matrix 4 gate-tiles x 16 kc x 64
// lanes x 8 u16 = 64 KiB. Wih @0, Whh @32768 (u16 units). 128 KiB total.
#define LDS_BYTES 131072

__device__ __forceinline__ u16 f2bf(float f) {
  unsigned u = __builtin_bit_cast(unsigned, f);
  u += 0x7fffu + ((u >> 16) & 1u);
  return (u16)(u >> 16);
}

__device__ __forceinline__ float sigm(float x) { return 1.0f / (1.0f + __expf(-x)); }
__device__ __forceinline__ float tanh_fast(float x) { return 1.0f - 2.0f / (__expf(2.0f * x) + 1.0f); }

// 16B coherent read via two 8B agent-scope relaxed loads (sc1: reads L3 directly)
__device__ __forceinline__ bf16x8 ld8_sc1(const u16* p) {
  u64x2 v;
  v.x = __hip_atomic_load((const unsigned long long*)p,       __ATOMIC_RELAXED, __HIP_MEMORY_SCOPE_AGENT);
  v.y = __hip_atomic_load((const unsigned long long*)(p + 4), __ATOMIC_RELAXED, __HIP_MEMORY_SCOPE_AGENT);
  return __builtin_bit_cast(bf16x8, v);
}

__device__ __forceinline__ unsigned long long pk2(float a, float b) {
  union { float f[2]; unsigned long long u; } v; v.f[0] = a; v.f[1] = b; return v.u;
}

// all-thread poll; monotonic counter; compiler barrier keeps later loads below.
// HW ordering is by data dependency (loads issued after poll-exit branch).
__device__ __forceinline__ void wait_ge(const int* p, int v) {
  while (__hip_atomic_load(p, __ATOMIC_RELAXED, __HIP_MEMORY_SCOPE_AGENT) < v)
    __builtin_amdgcn_s_sleep(1);
  __asm__ __volatile__("" ::: "memory");
}

__global__ __launch_bounds__(256) void cast_x_kernel(const float* __restrict__ x, u16* __restrict__ xbf) {
  unsigned i = (blockIdx.x * 256u + threadIdx.x) * 4u;
  float4_t v = *(const float4_t*)(x + i);
  unsigned p0 = (unsigned)f2bf(v.x) | ((unsigned)f2bf(v.y) << 16);
  unsigned p1 = (unsigned)f2bf(v.z) | ((unsigned)f2bf(v.w) << 16);
  uint2 p; p.x = p0; p.y = p1;
  *(uint2*)(xbf + i) = p;
}

__global__ __launch_bounds__(256) void init_kernel(const float* __restrict__ h0,
                                                   u16* __restrict__ h1s, u16* __restrict__ h2s,
                                                   int* __restrict__ flg) {
  unsigned idx = blockIdx.x * 256u + threadIdx.x;   // < 131072
  unsigned l = idx >> 16;
  unsigned pos = idx & 65535u;
  u16* dst = (l == 0 ? h1s : h2s) + 3 * BH + pos;   // slot 3 = "h[-1]"
  *dst = f2bf(h0[idx]);                             // end-of-kernel release flushes to L3
  if (idx < NFLAG_INTS) {
    int v = 0;
    if (idx == 0 || idx == F_RDY1) v = 64;          // rdy[l] entry for t=-1
    else if (idx == F_CON0 || idx == F_CON0 + 16 ||
             idx == F_CON0 + 32 || idx == F_CON0 + 48) v = 128;  // clearance t<4
    flg[idx] = v;
  }
}

// 256 blocks = 2 layers x 64 column-pairs x 2 K-halves (as R5), but NO global
// barrier: point-to-point dataflow flags (rdy/con/pflag/pdone), 4 h-slots.
// All inter-block data moves via the verified sc1 write-through + drained-flag
// protocol; all polls are agent-scope relaxed loads of monotonic counters.
__global__ __launch_bounds__(256, 1) void lstm_kernel(
    const float* __restrict__ Wih, const float* __restrict__ Whh,
    const float* __restrict__ bias, const float* __restrict__ c0,
    const u16* __restrict__ xbf,
    u16* __restrict__ h1s, u16* __restrict__ h2s,
    float* __restrict__ out, int* __restrict__ flg, char* __restrict__ part)
{
  extern __shared__ __align__(16) char smem_raw[];
  u16* lw = (u16*)smem_raw;
  const int tid = threadIdx.x;
  const int bid = blockIdx.x;
  const int layer = bid >> 7;
  const int lb = bid & 127;
  const int p = lb >> 1;
  const int half = lb & 1;
  const int pg = layer * 64 + p;            // global pair id 0..127
  const int pg16 = pg * 16;
  const int jbase16 = p * 16;               // hidden-column base of the tile
  const int kbase = half * 512;             // K-half owned by this block
  const bool prim = (half == 0);

  // ---- stage weight K-half into LDS (fp32 -> bf16), MFMA fragment order
  const float* WihL = Wih + (size_t)layer * 4096 * 1024;
  const float* WhhL = Whh + (size_t)layer * 4096 * 1024;
  for (int idx = tid; idx < 8192; idx += 256) {
    int n4 = idx >> 7;                      // 0..63 : gate*16 + lnt
    int k4 = (idx & 127) * 4;               // 0..508
    int gate = n4 >> 4, lnt = n4 & 15;
    size_t grow = (size_t)(gate * 1024 + jbase16 + lnt) * 1024 + kbase + k4;
    float4_t a = *(const float4_t*)(WihL + grow);
    float4_t b = *(const float4_t*)(WhhL + grow);
    int kc = k4 >> 5, q = (k4 & 31) >> 3, e = k4 & 7;   // e in {0,4}
    int di = gate * 8192 + kc * 512 + (q * 16 + lnt) * 8 + e;
    u16* d0 = lw + di;                      // Wih
    u16* d1 = lw + 32768 + di;              // Whh
    d0[0] = f2bf(a.x); d0[1] = f2bf(a.y); d0[2] = f2bf(a.z); d0[3] = f2bf(a.w);
    d1[0] = f2bf(b.x); d1[1] = f2bf(b.y); d1[2] = f2bf(b.z); d1[3] = f2bf(b.w);
  }

  const int lane = tid & 63;
  const int w = tid >> 6;                   // wave id: M-tile (16 batch rows)
  const int q = lane >> 4;                  // quad
  const int ln = lane & 15;
  const int arow = w * 16 + ln;             // batch row for A-frag loads
  const int koff = q * 8;                   // k-element offset within 32-chunk
  const int col16 = jbase16 + ln;           // hidden column (all lanes active)
  const int mrow0 = w * 16 + q * 4;         // C-frag rows mrow0 + r

  float bn[4];
  float c[4];
  if (prim) {
    const float* bL = bias + layer * 4096;
#pragma unroll
    for (int g = 0; g < 4; ++g) bn[g] = bL[g * 1024 + col16];
    const float* c0L = c0 + (size_t)layer * BH;
#pragma unroll
    for (int r = 0; r < 4; ++r) c[r] = c0L[(mrow0 + r) * 1024 + col16];
  }

  u16* mySlot = (layer == 0) ? h1s : h2s;
  const size_t OUT_HN = (size_t)TT * BH;
  const size_t OUT_CN = OUT_HN + 2 * BH;

  const u16* pW = lw + lane * 8;            // Wih tiles: + gate*8192 + kc*512
  const u16* pH = pW + 32768;               // Whh tiles

  __syncthreads();

  for (int t = 0; t < TT; ++t) {
    bf16x8 a0[16], a1[16];
    if (layer == 0) {
      // x[t] has no dependency: issue immediately, hide under the rdy wait
      const u16* a0p = xbf + (size_t)t * BH + arow * 1024 + kbase + koff;
#pragma unroll
      for (int kc = 0; kc < 16; ++kc) a0[kc] = *(const bf16x8*)(a0p + kc * 32);
      wait_ge(&flg[t * 16], 64);            // rdy0 entry t == h1[t-1] ready
      const u16* a1p = h1s + (size_t)((t - 1) & 3) * BH + arow * 1024 + kbase + koff;
#pragma unroll
      for (int kc = 0; kc < 16; ++kc) a1[kc] = ld8_sc1(a1p + kc * 32);
    } else {
      wait_ge(&flg[F_RDY1 + t * 16], 64);   // h2[t-1] ready (usually already)
      const u16* a1p = h2s + (size_t)((t - 1) & 3) * BH + arow * 1024 + kbase + koff;
#pragma unroll
      for (int kc = 0; kc < 16; ++kc) a1[kc] = ld8_sc1(a1p + kc * 32);
      wait_ge(&flg[(t + 1) * 16], 64);      // rdy0 entry t+1 == h1[t] ready
      const u16* a0p = h1s + (size_t)(t & 3) * BH + arow * 1024 + kbase + koff;
#pragma unroll
      for (int kc = 0; kc < 16; ++kc) a0[kc] = ld8_sc1(a0p + kc * 32);
    }

    f32x4 acc[4];
#pragma unroll
    for (int g = 0; g < 4; ++g) acc[g] = (f32x4){0.f, 0.f, 0.f, 0.f};

    if (layer == 0) {                       // a0 (x) arrived first
#pragma unroll
      for (int kc = 0; kc < 16; ++kc)
#pragma unroll
        for (int g = 0; g < 4; ++g) {
          bf16x8 b = *(const bf16x8*)(pW + g * 8192 + kc * 512);
          acc[g] = __builtin_amdgcn_mfma_f32_16x16x32_bf16(a0[kc], b, acc[g], 0, 0, 0);
        }
#pragma unroll
      for (int kc = 0; kc < 16; ++kc)
#pragma unroll
        for (int g = 0; g < 4; ++g) {
          bf16x8 b = *(const bf16x8*)(pH + g * 8192 + kc * 512);
          acc[g] = __builtin_amdgcn_mfma_f32_16x16x32_bf16(a1[kc], b, acc[g], 0, 0, 0);
        }
    } else {                                // a1 (own h) arrived first
#pragma unroll
      for (int kc = 0; kc < 16; ++kc)
#pragma unroll
        for (int g = 0; g < 4; ++g) {
          bf16x8 b = *(const bf16x8*)(pH + g * 8192 + kc * 512);
          acc[g] = __builtin_amdgcn_mfma_f32_16x16x32_bf16(a1[kc], b, acc[g], 0, 0, 0);
        }
#pragma unroll
      for (int kc = 0; kc < 16; ++kc)
#pragma unroll
        for (int g = 0; g < 4; ++g) {
          bf16x8 b = *(const bf16x8*)(pW + g * 8192 + kc * 512);
          acc[g] = __builtin_amdgcn_mfma_f32_16x16x32_bf16(a0[kc], b, acc[g], 0, 0, 0);
        }
    }

    if (!prim) {
      // ---- secondary: wait partial-slot clearance, ship fp32 partial via L3
      wait_ge(&flg[F_PDONE + pg16], t - 1);
      char* pb = part + (size_t)pg * 32768 + (size_t)(t & 1) * 16384 + (size_t)tid * 64;
#pragma unroll
      for (int g = 0; g < 4; ++g) {
        __hip_atomic_store((unsigned long long*)(pb + g * 16),
                           pk2(acc[g][0], acc[g][1]),
                           __ATOMIC_RELAXED, __HIP_MEMORY_SCOPE_AGENT);
        __hip_atomic_store((unsigned long long*)(pb + g * 16 + 8),
                           pk2(acc[g][2], acc[g][3]),
                           __ATOMIC_RELAXED, __HIP_MEMORY_SCOPE_AGENT);
      }
      __syncthreads();                      // drain partial stores (and all loads)
      if (tid == 0) {
        __hip_atomic_store(&flg[F_PFLAG + pg16], t + 1,
                           __ATOMIC_RELAXED, __HIP_MEMORY_SCOPE_AGENT);
        if (layer == 1)                     // consumed h1[t]
          __hip_atomic_fetch_add(&flg[F_CON0 + (t + 4) * 16], 1,
                                 __ATOMIC_RELAXED, __HIP_MEMORY_SCOPE_AGENT);
      }
    } else {
      // ---- primary: partner partial, combine, epilogue, h stores
      wait_ge(&flg[F_PFLAG + pg16], t + 1);
      const char* pb = part + (size_t)pg * 32768 + (size_t)(t & 1) * 16384 + (size_t)tid * 64;
      float gg[4][4];
#pragma unroll
      for (int g = 0; g < 4; ++g) {
        unsigned long long v0 = __hip_atomic_load((const unsigned long long*)(pb + g * 16),
                                                  __ATOMIC_RELAXED, __HIP_MEMORY_SCOPE_AGENT);
        unsigned long long v1 = __hip_atomic_load((const unsigned long long*)(pb + g * 16 + 8),
                                                  __ATOMIC_RELAXED, __HIP_MEMORY_SCOPE_AGENT);
        union { unsigned long long u; float f[2]; } x0, x1;
        x0.u = v0; x1.u = v1;
        gg[g][0] = acc[g][0] + x0.f[0] + bn[g];
        gg[g][1] = acc[g][1] + x0.f[1] + bn[g];
        gg[g][2] = acc[g][2] + x1.f[0] + bn[g];
        gg[g][3] = acc[g][3] + x1.f[1] + bn[g];
      }
      float hn[4];
#pragma unroll
      for (int r = 0; r < 4; ++r) {
        float iv = sigm(gg[0][r]);
        float fv = sigm(gg[1][r]);
        float gv = tanh_fast(gg[2][r]);
        float ov = sigm(gg[3][r]);
        c[r] = fv * c[r] + iv * gv;
        hn[r] = ov * tanh_fast(c[r]);
      }
      if (layer == 0)                       // slot write-clearance (4-step slack)
        wait_ge(&flg[F_CON0 + t * 16], 128);
      u16* hdst = mySlot + (size_t)(t & 3) * BH;
#pragma unroll
      for (int r = 0; r < 4; ++r)           // write-through to L3 (sc1)
        __hip_atomic_store(&hdst[(mrow0 + r) * 1024 + col16], f2bf(hn[r]),
                           __ATOMIC_RELAXED, __HIP_MEMORY_SCOPE_AGENT);
      if (layer == 1) {
        float* od = out + (size_t)t * BH;
#pragma unroll
        for (int r = 0; r < 4; ++r) od[(mrow0 + r) * 1024 + col16] = hn[r];
      }
      if (t == TT - 1) {
#pragma unroll
        for (int r = 0; r < 4; ++r) {
          out[OUT_HN + (size_t)layer * BH + (mrow0 + r) * 1024 + col16] = hn[r];
          out[OUT_CN + (size_t)layer * BH + (mrow0 + r) * 1024 + col16] = c[r];
        }
      }
      __syncthreads();                      // drain h stores across all waves
      if (tid == 0) {
        __hip_atomic_fetch_add(&flg[(layer ? F_RDY1 : 0) + (t + 1) * 16], 1,
                               __ATOMIC_RELAXED, __HIP_MEMORY_SCOPE_AGENT);
        __hip_atomic_store(&flg[F_PDONE + pg16], t + 1,
                           __ATOMIC_RELAXED, __HIP_MEMORY_SCOPE_AGENT);
        if (layer == 1)                     // consumed h1[t]
          __hip_atomic_fetch_add(&flg[F_CON0 + (t + 4) * 16], 1,
                                 __ATOMIC_RELAXED, __HIP_MEMORY_SCOPE_AGENT);
      }
    }
  }
}

extern "C" void kernel_launch(void* const* d_in, const int* in_sizes, int n_in,
                              void* d_out, int out_size, void* d_ws, size_t ws_size,
                              hipStream_t stream) {
  const float* x    = (const float*)d_in[0];
  const float* Wih  = (const float*)d_in[1];
  const float* Whh  = (const float*)d_in[2];
  const float* bias = (const float*)d_in[3];
  const float* h0   = (const float*)d_in[4];
  const float* c0   = (const float*)d_in[5];
  float* out = (float*)d_out;
  char* ws = (char*)d_ws;
  u16* xbf   = (u16*)(ws + WS_XBF);
  u16* h1s   = (u16*)(ws + WS_H1);
  u16* h2s   = (u16*)(ws + WS_H2);
  int* flg   = (int*)(ws + WS_FLG);
  char* part = (char*)(ws + WS_PART);

  hipFuncSetAttribute((const void*)lstm_kernel,
                      hipFuncAttributeMaxDynamicSharedMemorySize, LDS_BYTES);

  cast_x_kernel<<<32768, 256, 0, stream>>>(x, xbf);
  init_kernel<<<512, 256, 0, stream>>>(h0, h1s, h2s, flg);
  lstm_kernel<<<NBLK, 256, LDS_BYTES, stream>>>(Wih, Whh, bias, c0, xbf, h1s, h2s,
                                                out, flg, part);
}

// Round 7
// 6068.524 us; speedup vs baseline: 1.5514x; 1.5514x over previous
//
#include <hip/hip_runtime.h>

#define TT 512
#define BH 65536            // B*H elements (64*1024)
#define NBLK 256

typedef unsigned short u16;
typedef __attribute__((ext_vector_type(8))) __bf16 bf16x8;
typedef __attribute__((ext_vector_type(4))) float f32x4;
typedef __attribute__((ext_vector_type(4))) float float4_t;
typedef __attribute__((ext_vector_type(2))) unsigned long long u64x2;

// workspace byte offsets
#define WS_XBF   0ull
#define WS_H1    67108864ull                 // x_bf16: 512*64*1024*2 B
#define WS_H2    (WS_H1 + 262144ull)         // 2 slots * BH * 2 B
#define WS_FLAGS (WS_H2 + 262144ull)         // 256 blocks * 32 ints (128 B apart)
#define WS_REL   (WS_FLAGS + 32768ull)       // release word, own line
#define WS_PCNT  (WS_REL + 256ull)           // 64 tile-groups * 16 ints (64 B apart)
#define WS_PART  (WS_PCNT + 4096ull)         // 64 tg * 4 kq * 32 KiB fp32 partials

// Weights in LDS, MFMA-fragment order: per matrix 8 ntiles x 8 kc x 64 lanes
// x 8 u16 = 64 KiB. Wih @0, Whh @32768 (u16 units). 128 KiB total.
#define LDS_BYTES 131072

__device__ __forceinline__ u16 f2bf(float f) {
  unsigned u = __builtin_bit_cast(unsigned, f);
  u += 0x7fffu + ((u >> 16) & 1u);
  return (u16)(u >> 16);
}

__device__ __forceinline__ float sigm(float x) { return 1.0f / (1.0f + __expf(-x)); }
__device__ __forceinline__ float tanh_fast(float x) { return 1.0f - 2.0f / (__expf(2.0f * x) + 1.0f); }

// coherent reads/writes through the L3 coherence point (verified protocol)
__device__ __forceinline__ bf16x8 ld8_sc1(const u16* p) {
  u64x2 v;
  v.x = __hip_atomic_load((const unsigned long long*)p,       __ATOMIC_RELAXED, __HIP_MEMORY_SCOPE_AGENT);
  v.y = __hip_atomic_load((const unsigned long long*)(p + 4), __ATOMIC_RELAXED, __HIP_MEMORY_SCOPE_AGENT);
  return __builtin_bit_cast(bf16x8, v);
}
__device__ __forceinline__ float4_t ld4f_sc1(const float* p) {
  u64x2 v;
  v.x = __hip_atomic_load((const unsigned long long*)p,       __ATOMIC_RELAXED, __HIP_MEMORY_SCOPE_AGENT);
  v.y = __hip_atomic_load((const unsigned long long*)(p + 2), __ATOMIC_RELAXED, __HIP_MEMORY_SCOPE_AGENT);
  return __builtin_bit_cast(float4_t, v);
}
__device__ __forceinline__ unsigned long long pk2(float a, float b) {
  union { float f[2]; unsigned long long u; } v; v.f[0] = a; v.f[1] = b; return v.u;
}

__global__ __launch_bounds__(256) void cast_x_kernel(const float* __restrict__ x, u16* __restrict__ xbf) {
  unsigned i = (blockIdx.x * 256u + threadIdx.x) * 4u;
  float4_t v = *(const float4_t*)(x + i);
  unsigned p0 = (unsigned)f2bf(v.x) | ((unsigned)f2bf(v.y) << 16);
  unsigned p1 = (unsigned)f2bf(v.z) | ((unsigned)f2bf(v.w) << 16);
  uint2 p; p.x = p0; p.y = p1;
  *(uint2*)(xbf + i) = p;
}

__global__ __launch_bounds__(256) void init_kernel(const float* __restrict__ h0,
                                                   u16* __restrict__ h1s, u16* __restrict__ h2s,
                                                   int* __restrict__ flags, int* __restrict__ rel,
                                                   int* __restrict__ pcnt) {
  unsigned idx = blockIdx.x * 256u + threadIdx.x;   // < 131072
  unsigned l = idx >> 16;
  unsigned pos = idx & 65535u;
  u16* dst = (l == 0 ? h1s : h2s) + BH + pos;       // slot 1 = "h[-1]"
  *dst = f2bf(h0[idx]);                             // end-of-kernel release flushes to L3
  if (idx < 8192) flags[idx] = 0;
  if (idx < 1024) pcnt[idx] = 0;
  if (idx == 0) rel[0] = 0;
}

// 256 blocks = 2 layers x 32 col-tiles (32 cols) x 4 K-quarters.
// Per block: 128 gate rows x 256 K of Wih+Whh in LDS (128 KiB); A-reads are
// 64 KiB/step (half of R5's 128 KiB -> MSHR x L3-latency bound halves).
// 4-way reduction: each block stores its full fp32 partial (single slot; the
// per-step global barrier makes same-step reuse safe), bumps pcnt after drain,
// polls pcnt==4(t+1), then reads its 16-row quarter from all 4 partials and
// runs the epilogue for those rows. All exchange via verified sc1 protocol.
__global__ __launch_bounds__(256, 1) void lstm_kernel(
    const float* __restrict__ Wih, const float* __restrict__ Whh,
    const float* __restrict__ bias, const float* __restrict__ c0,
    const u16* __restrict__ xbf,
    u16* __restrict__ h1s, u16* __restrict__ h2s,
    float* __restrict__ out, int* __restrict__ flags, int* __restrict__ pcnt,
    int* __restrict__ rel, float* __restrict__ part)
{
  extern __shared__ __align__(16) char smem_raw[];
  u16* lw = (u16*)smem_raw;
  const int tid = threadIdx.x;
  const int bid = blockIdx.x;
  const int layer = bid >> 7;
  const int lb = bid & 127;
  const int tile = lb >> 2;                 // 0..31
  const int kq = lb & 3;                    // K-quarter
  const int tg = layer * 32 + tile;         // tile-group id 0..63
  const int kbase = kq * 256;

  // ---- stage weight slice into LDS (fp32 -> bf16), MFMA fragment order:
  // arr[ntile][kc][lane][8]; ntile = gate*2+ch covers cols tile*32+ch*16+lnt
  const float* WihL = Wih + (size_t)layer * 4096 * 1024;
  const float* WhhL = Whh + (size_t)layer * 4096 * 1024;
  for (int idx = tid; idx < 8192; idx += 256) {
    int n4 = idx >> 6;                      // 0..127 gate-row index
    int k4 = (idx & 63) * 4;                // 0..252
    int nt = n4 >> 4, lnt = n4 & 15;
    int gate = nt >> 1, ch = nt & 1;
    size_t grow = (size_t)(gate * 1024 + tile * 32 + ch * 16 + lnt) * 1024 + kbase + k4;
    float4_t a = *(const float4_t*)(WihL + grow);
    float4_t b = *(const float4_t*)(WhhL + grow);
    int kc = k4 >> 5, q = (k4 & 31) >> 3, e = k4 & 7;   // e in {0,4}
    int di = nt * 4096 + kc * 512 + (q * 16 + lnt) * 8 + e;
    u16* d0 = lw + di;                      // Wih
    u16* d1 = lw + 32768 + di;              // Whh
    d0[0] = f2bf(a.x); d0[1] = f2bf(a.y); d0[2] = f2bf(a.z); d0[3] = f2bf(a.w);
    d1[0] = f2bf(b.x); d1[1] = f2bf(b.y); d1[2] = f2bf(b.z); d1[3] = f2bf(b.w);
  }

  const int lane = tid & 63;
  const int w = tid >> 6;                   // wave id: M-tile (16 batch rows)
  const int q = lane >> 4;                  // quad
  const int ln = lane & 15;
  const int arow = w * 16 + ln;             // batch row for A-frag loads
  const int koff = q * 8;

  // epilogue mapping: this block handles batch rows [kq*16, kq*16+16)
  const int rloc = tid >> 4;                // 0..15
  const int cloc = tid & 15;                // 0..15
  const int erow = kq * 16 + rloc;          // batch row for epilogue

  float bn[4][2];
  float c[2];
  {
    const float* bL = bias + layer * 4096;
#pragma unroll
    for (int g = 0; g < 4; ++g)
#pragma unroll
      for (int ch = 0; ch < 2; ++ch)
        bn[g][ch] = bL[g * 1024 + tile * 32 + ch * 16 + cloc];
    const float* c0L = c0 + (size_t)layer * BH;
#pragma unroll
    for (int ch = 0; ch < 2; ++ch)
      c[ch] = c0L[erow * 1024 + tile * 32 + ch * 16 + cloc];
  }

  u16* mySlot = (layer == 0) ? h1s : h2s;
  const size_t OUT_HN = (size_t)TT * BH;
  const size_t OUT_CN = OUT_HN + 2 * BH;

  const u16* pW = lw + lane * 8;            // Wih frags: + nt*4096 + kc*512
  const u16* pH = pW + 32768;               // Whh frags
  float* myPart = part + ((size_t)tg * 4 + kq) * 8192;   // this block's partial
  const float* tgPart = part + (size_t)tg * 4 * 8192;    // tile-group partial base

  __syncthreads();

  for (int it = 0; it <= TT; ++it) {
    const int t = (layer == 0) ? it : (it - 1);
    if (t >= 0 && t < TT) {
      // ---- prefetch all A-fragments of both streams (K-quarter) into regs
      bf16x8 a0[8], a1[8];
      if (layer == 0) {                     // x: clean/cacheable
        const u16* a0p = xbf + (size_t)t * BH + arow * 1024 + kbase + koff;
#pragma unroll
        for (int kc = 0; kc < 8; ++kc) a0[kc] = *(const bf16x8*)(a0p + kc * 32);
      } else {                              // h1 from layer0: coherent
        const u16* a0p = h1s + (size_t)(t & 1) * BH + arow * 1024 + kbase + koff;
#pragma unroll
        for (int kc = 0; kc < 8; ++kc) a0[kc] = ld8_sc1(a0p + kc * 32);
      }
      {
        const u16* a1p = mySlot + (size_t)((t - 1) & 1) * BH + arow * 1024 + kbase + koff;
#pragma unroll
        for (int kc = 0; kc < 8; ++kc) a1[kc] = ld8_sc1(a1p + kc * 32);
      }

      f32x4 acc[8];
#pragma unroll
      for (int n = 0; n < 8; ++n) acc[n] = (f32x4){0.f, 0.f, 0.f, 0.f};

#pragma unroll
      for (int kc = 0; kc < 8; ++kc)
#pragma unroll
        for (int n = 0; n < 8; ++n) {
          bf16x8 b = *(const bf16x8*)(pW + n * 4096 + kc * 512);
          acc[n] = __builtin_amdgcn_mfma_f32_16x16x32_bf16(a0[kc], b, acc[n], 0, 0, 0);
        }
#pragma unroll
      for (int kc = 0; kc < 8; ++kc)
#pragma unroll
        for (int n = 0; n < 8; ++n) {
          bf16x8 b = *(const bf16x8*)(pH + n * 4096 + kc * 512);
          acc[n] = __builtin_amdgcn_mfma_f32_16x16x32_bf16(a1[kc], b, acc[n], 0, 0, 0);
        }

      // ---- write full fp32 partial, gates interleaved: [row][colw*4 + gate]
      // acc[n][r]: row = w*16+q*4+r, colw = (n&1)*16+ln, gate = n>>1
#pragma unroll
      for (int ch = 0; ch < 2; ++ch) {
        int colw = ch * 16 + ln;
#pragma unroll
        for (int r = 0; r < 4; ++r) {
          int base = (w * 16 + q * 4 + r) * 128 + colw * 4;
          __hip_atomic_store((unsigned long long*)(myPart + base),
                             pk2(acc[0 + ch][r], acc[2 + ch][r]),
                             __ATOMIC_RELAXED, __HIP_MEMORY_SCOPE_AGENT);
          __hip_atomic_store((unsigned long long*)(myPart + base + 2),
                             pk2(acc[4 + ch][r], acc[6 + ch][r]),
                             __ATOMIC_RELAXED, __HIP_MEMORY_SCOPE_AGENT);
        }
      }
      __syncthreads();                      // drain partial stores (all waves)
      if (tid == 0) {
        __hip_atomic_fetch_add(&pcnt[tg * 16], 1,
                               __ATOMIC_RELAXED, __HIP_MEMORY_SCOPE_AGENT);
        while (__hip_atomic_load(&pcnt[tg * 16], __ATOMIC_RELAXED,
                                 __HIP_MEMORY_SCOPE_AGENT) < 4 * (t + 1))
          __builtin_amdgcn_s_sleep(1);
      }
      __syncthreads();                      // whole tile-group's partials at L3

      // ---- epilogue for this block's 16 batch rows
#pragma unroll
      for (int ch = 0; ch < 2; ++ch) {
        int fidx = erow * 128 + (ch * 16 + cloc) * 4;
        float4_t s0 = ld4f_sc1(tgPart + fidx);
        float4_t s1 = ld4f_sc1(tgPart + 8192 + fidx);
        float4_t s2 = ld4f_sc1(tgPart + 16384 + fidx);
        float4_t s3 = ld4f_sc1(tgPart + 24576 + fidx);
        float gi = s0.x + s1.x + s2.x + s3.x + bn[0][ch];
        float gf = s0.y + s1.y + s2.y + s3.y + bn[1][ch];
        float gg = s0.z + s1.z + s2.z + s3.z + bn[2][ch];
        float go = s0.w + s1.w + s2.w + s3.w + bn[3][ch];
        float iv = sigm(gi), fv = sigm(gf), gv = tanh_fast(gg), ov = sigm(go);
        c[ch] = fv * c[ch] + iv * gv;
        float hn = ov * tanh_fast(c[ch]);
        int col = tile * 32 + ch * 16 + cloc;
        u16* hdst = mySlot + (size_t)(t & 1) * BH;
        __hip_atomic_store(&hdst[erow * 1024 + col], f2bf(hn),
                           __ATOMIC_RELAXED, __HIP_MEMORY_SCOPE_AGENT);
        if (layer == 1)
          out[(size_t)t * BH + erow * 1024 + col] = hn;
        if (t == TT - 1) {
          out[OUT_HN + (size_t)layer * BH + erow * 1024 + col] = hn;
          out[OUT_CN + (size_t)layer * BH + erow * 1024 + col] = c[ch];
        }
      }
    }

    // ---- grid barrier: flags + release word; NO agent fences. sc1 stores are
    // visible at L3 once vmcnt retires, which __syncthreads enforces.
    if (it < TT) {
      __syncthreads();
      if (bid == 0) {
        if (tid > 0) {
          while (__hip_atomic_load(&flags[tid * 32], __ATOMIC_RELAXED,
                                   __HIP_MEMORY_SCOPE_AGENT) < it + 1)
            __builtin_amdgcn_s_sleep(1);
        }
        __syncthreads();                    // all arrivals seen
        if (tid == 0)
          __hip_atomic_store(rel, it + 1, __ATOMIC_RELAXED, __HIP_MEMORY_SCOPE_AGENT);
      } else {
        if (tid == 0) {
          __hip_atomic_store(&flags[bid * 32], it + 1, __ATOMIC_RELAXED,
                             __HIP_MEMORY_SCOPE_AGENT);
          while (__hip_atomic_load(rel, __ATOMIC_RELAXED,
                                   __HIP_MEMORY_SCOPE_AGENT) < it + 1)
            __builtin_amdgcn_s_sleep(1);
        }
        __syncthreads();
      }
      // compiler-reorder guard only (workgroup scope: waitcnt, no cache ops)
      __builtin_amdgcn_fence(__ATOMIC_ACQUIRE, "workgroup");
    }
  }
}

extern "C" void kernel_launch(void* const* d_in, const int* in_sizes, int n_in,
                              void* d_out, int out_size, void* d_ws, size_t ws_size,
                              hipStream_t stream) {
  const float* x    = (const float*)d_in[0];
  const float* Wih  = (const float*)d_in[1];
  const float* Whh  = (const float*)d_in[2];
  const float* bias = (const float*)d_in[3];
  const float* h0   = (const float*)d_in[4];
  const float* c0   = (const float*)d_in[5];
  float* out = (float*)d_out;
  char* ws = (char*)d_ws;
  u16* xbf   = (u16*)(ws + WS_XBF);
  u16* h1s   = (u16*)(ws + WS_H1);
  u16* h2s   = (u16*)(ws + WS_H2);
  int* flags = (int*)(ws + WS_FLAGS);
  int* rel   = (int*)(ws + WS_REL);
  int* pcnt  = (int*)(ws + WS_PCNT);
  float* part = (float*)(ws + WS_PART);

  hipFuncSetAttribute((const void*)lstm_kernel,
                      hipFuncAttributeMaxDynamicSharedMemorySize, LDS_BYTES);

  cast_x_kernel<<<32768, 256, 0, stream>>>(x, xbf);
  init_kernel<<<512, 256, 0, stream>>>(h0, h1s, h2s, flags, rel, pcnt);
  lstm_kernel<<<NBLK, 256, LDS_BYTES, stream>>>(Wih, Whh, bias, c0, xbf, h1s, h2s,
                                                out, flags, pcnt, rel, part);
}